// Round 9
// baseline (79.516 us; speedup 1.0000x reference)
//
#include <hip/hip_runtime.h>

#define NB 8
#define NT 2048
#define NC 1024
#define NH 64

typedef __bf16 bf16x8 __attribute__((ext_vector_type(8)));
typedef float f32x4 __attribute__((ext_vector_type(4)));

static __device__ __forceinline__ float4 ldf4(const float* p) {
  return *reinterpret_cast<const float4*>(p);
}
static __device__ __forceinline__ bf16x8 ldb8(const __bf16* p) {
  return *reinterpret_cast<const bf16x8*>(p);
}
static __device__ __forceinline__ unsigned pack_bf2(float a, float b) {
  unsigned short ua = __builtin_bit_cast(unsigned short, (__bf16)a);
  unsigned short ub = __builtin_bit_cast(unsigned short, (__bf16)b);
  return (unsigned)ua | ((unsigned)ub << 16);
}
static __device__ __forceinline__ bf16x8 cvt8(float4 a, float4 b) {
  bf16x8 r;
  r[0] = (__bf16)a.x; r[1] = (__bf16)a.y; r[2] = (__bf16)a.z; r[3] = (__bf16)a.w;
  r[4] = (__bf16)b.x; r[5] = (__bf16)b.y; r[6] = (__bf16)b.z; r[7] = (__bf16)b.w;
  return r;
}
// async global->LDS DMA, 16B/lane: LDS dest = wave-uniform base + lane*16
static __device__ __forceinline__ void gload16f(const float* g, float* l) {
  __builtin_amdgcn_global_load_lds(
      (const __attribute__((address_space(1))) unsigned int*)g,
      (__attribute__((address_space(3))) unsigned int*)l, 16, 0, 0);
}

// ---------------------------------------------------------------------------
// Kernel A: Wt[192][1024] bf16 = transpose+convert of Wq|Wk|Wv (fp32 [1024][64]).
// ---------------------------------------------------------------------------
__global__ __launch_bounds__(256) void wt_kernel(
    const float* __restrict__ Wq, const float* __restrict__ Wk,
    const float* __restrict__ Wv, __bf16* __restrict__ wt) {
  __shared__ __bf16 tl[64][72];
  const int tid = threadIdx.x;
  const int mat = blockIdx.x >> 4;
  const int k0 = (blockIdx.x & 15) * 64;
  const float* W = (mat == 0) ? Wq : (mat == 1) ? Wk : Wv;
#pragma unroll
  for (int it = 0; it < 4; ++it) {
    int f = tid + it * 256;
    int kk = f >> 4, c4 = (f & 15) * 4;
    float4 w = ldf4(&W[(k0 + kk) * NH + c4]);
    tl[c4 + 0][kk] = (__bf16)w.x;
    tl[c4 + 1][kk] = (__bf16)w.y;
    tl[c4 + 2][kk] = (__bf16)w.z;
    tl[c4 + 3][kk] = (__bf16)w.w;
  }
  __syncthreads();
#pragma unroll
  for (int it = 0; it < 2; ++it) {
    int f = tid + it * 256;
    int h = f >> 3, k8 = (f & 7) * 8;
    *reinterpret_cast<bf16x8*>(&wt[(mat * 64 + h) * NC + k0 + k8]) =
        *reinterpret_cast<const bf16x8*>(&tl[h][k8]);
  }
}

// ---------------------------------------------------------------------------
// Kernel B: q,k (bf16 row-major) and v^T (bf16 [b][h][t]) = x @ W via MFMA.
// BARRIER-FREE per-wave pipeline. 512 blocks x 256 thr (4 waves, 2 blocks/CU).
// Wave (wr=w>>1, wc=w&1): rows row0+wr*16+[0,16), cols wc*96+[0,96).
// Per chunk (BK=64): wave stages its OWN A-tile (16x64 fp32) via 4
// global_load_lds into wave-private As[w][2][16][64] (quad-XOR source
// pre-swizzle + XOR read = 2-way banks), prefetches 12 B-frags to regs,
// then s_waitcnt vmcnt(16) (counted: next chunk's 16 ops stay in flight)
// + sched_barrier(0) fence (rule 18), then 12 MFMAs. No __syncthreads in
// the loop -> waves free-run, TLP hides latency.
// ---------------------------------------------------------------------------
__global__ __launch_bounds__(256, 2) void qkv_mfma_kernel(
    const float* __restrict__ x, const __bf16* __restrict__ wt,
    __bf16* __restrict__ qb, __bf16* __restrict__ kb, __bf16* __restrict__ vt) {
  __shared__ float As[4][2][16][64];  // 32 KB, wave-private double buffer
  __shared__ __bf16 vls[64][40];      // v transpose epilogue
  const int tid = threadIdx.x;
  const int lane = tid & 63;
  const int w = tid >> 6;           // 0..3
  const int wr = w >> 1, wc = w & 1;
  const int row0 = blockIdx.x * 32;
  const int l15 = lane & 15, lg = lane >> 4;

  f32x4 acc[6];
#pragma unroll
  for (int j = 0; j < 6; ++j) acc[j] = (f32x4){0.f, 0.f, 0.f, 0.f};

  // A-DMA per-lane swizzled sources: instr it stages rows it*4+lg (lg=lane>>4),
  // lane quad l15 taken from global quad (l15 ^ row_local).
  const float* xs[4];
#pragma unroll
  for (int it = 0; it < 4; ++it) {
    const int rl = it * 4 + lg;  // row_local 0..15
    xs[it] = &x[(size_t)(row0 + wr * 16 + rl) * NC + ((l15 ^ rl) * 4)];
  }
  // B per-lane bases: col = wc*96 + nt*16 + l15, k-octet lg*8
  const __bf16* wb[6];
#pragma unroll
  for (int nt = 0; nt < 6; ++nt)
    wb[nt] = &wt[(size_t)(wc * 96 + nt * 16 + l15) * NC + lg * 8];

  float* const abase = &As[w][0][0][0];  // wave-uniform

  bf16x8 bcur[6][2], bnxt[6][2];

  // prologue: stage chunk 0 (4 DMA + 12 B loads = 16 outstanding)
#pragma unroll
  for (int it = 0; it < 4; ++it) gload16f(xs[it], abase + it * 256);
#pragma unroll
  for (int nt = 0; nt < 6; ++nt) {
    bcur[nt][0] = ldb8(wb[nt]);
    bcur[nt][1] = ldb8(wb[nt] + 32);
  }

  for (int ch = 0; ch < 16; ++ch) {
    const int cur = ch & 1;
    // issue chunk ch+1 staging (tail-clamped, unconditional: no sinking)
    const int chn = (ch < 15) ? ch + 1 : 15;
    const int offn = chn * 64;
    float* ad = abase + (1 - cur) * 1024;
#pragma unroll
    for (int it = 0; it < 4; ++it) gload16f(xs[it] + offn, ad + it * 256);
#pragma unroll
    for (int nt = 0; nt < 6; ++nt) {
      bnxt[nt][0] = ldb8(wb[nt] + offn);
      bnxt[nt][1] = ldb8(wb[nt] + offn + 32);
    }
    // wait for chunk ch's 16 ops only; the 16 just issued stay in flight
    asm volatile("s_waitcnt vmcnt(16)" ::: "memory");
    __builtin_amdgcn_sched_barrier(0);
    // compute chunk ch
    const float* ab = abase + cur * 1024;
#pragma unroll
    for (int kk = 0; kk < 2; ++kk) {
      const int g = kk * 8 + lg * 2;
      float4 p0 = *reinterpret_cast<const float4*>(ab + l15 * 64 + ((g ^ l15) * 4));
      float4 p1 = *reinterpret_cast<const float4*>(ab + l15 * 64 + (((g + 1) ^ l15) * 4));
      bf16x8 af = cvt8(p0, p1);
#pragma unroll
      for (int nt = 0; nt < 6; ++nt)
        acc[nt] = __builtin_amdgcn_mfma_f32_16x16x32_bf16(af, bcur[nt][kk], acc[nt], 0, 0, 0);
    }
    // rotate prefetched B regs in
#pragma unroll
    for (int nt = 0; nt < 6; ++nt) {
      bcur[nt][0] = bnxt[nt][0];
      bcur[nt][1] = bnxt[nt][1];
    }
  }

  // epilogue: D layout col=l15, row=lg*4+r. mat uniform per (wc,nt).
#pragma unroll
  for (int nt = 0; nt < 6; ++nt) {
    const int colbase = wc * 96 + nt * 16;  // wave-uniform, multiple of 16
    const int mat = colbase >> 6;
    if (mat == 0) {
      const int h = colbase + l15;
#pragma unroll
      for (int r = 0; r < 4; ++r) {
        int row = row0 + wr * 16 + lg * 4 + r;
        qb[row * NH + h] = (__bf16)(acc[nt][r] * 0.125f);  // pre-scale q
      }
    } else if (mat == 1) {
      const int h = (colbase & 63) + l15;
#pragma unroll
      for (int r = 0; r < 4; ++r) {
        int row = row0 + wr * 16 + lg * 4 + r;
        kb[row * NH + h] = (__bf16)acc[nt][r];
      }
    } else {
      const int h = (colbase - 128) + l15;
      ushort4 pk;
      pk.x = __builtin_bit_cast(unsigned short, (__bf16)acc[nt][0]);
      pk.y = __builtin_bit_cast(unsigned short, (__bf16)acc[nt][1]);
      pk.z = __builtin_bit_cast(unsigned short, (__bf16)acc[nt][2]);
      pk.w = __builtin_bit_cast(unsigned short, (__bf16)acc[nt][3]);
      *reinterpret_cast<ushort4*>(&vls[h][wr * 16 + lg * 4]) = pk;
    }
  }
  __syncthreads();
  // cooperative coalesced v^T store: 64 h x 32 t, one 16B store per thread
  {
    int h = tid >> 2, t8 = (tid & 3) * 8;
    int bb = row0 >> 11;
    int t0l = row0 & (NT - 1);
    *reinterpret_cast<bf16x8*>(&vt[((size_t)bb * NH + h) * NT + t0l + t8]) =
        *reinterpret_cast<const bf16x8*>(&vls[h][t8]);
  }
}

// ---------------------------------------------------------------------------
// Kernel C: causal flash attention via MFMA, intra-block KV split.
// (exact R4 version) Grid dim3(64,8); qt = (y<4) ? 63-x : x. 4 waves;
// wave w handles KV chunks c = w, w+4, ... setprio(1) around MFMA clusters.
// ---------------------------------------------------------------------------
__global__ __launch_bounds__(256, 2) void attn_mfma_kernel(
    const __bf16* __restrict__ qb, const __bf16* __restrict__ kb,
    const __bf16* __restrict__ vt, float* __restrict__ out) {
  __shared__ __bf16 ps[4][32][72];
  __shared__ float obuf[4][32][68];
  __shared__ float msh[4][32], lsh[4][32];
  const int tid = threadIdx.x;
  const int lane = tid & 63;
  const int w = tid >> 6;
  const int l15 = lane & 15, lg = lane >> 4;
  const int b = blockIdx.y;
  const int qt = (blockIdx.y < 4) ? (63 - (int)blockIdx.x) : (int)blockIdx.x;
  const int q0 = qt * 32;
  const size_t bT = (size_t)b * NT;

  bf16x8 qf[2][2];
#pragma unroll
  for (int ct = 0; ct < 2; ++ct)
#pragma unroll
    for (int kh = 0; kh < 2; ++kh)
      qf[ct][kh] = *reinterpret_cast<const bf16x8*>(
          &qb[(bT + q0 + ct * 16 + l15) * NH + kh * 32 + lg * 8]);

  float m[2] = {-1e30f, -1e30f};
  float lsum[2] = {0.f, 0.f};
  f32x4 o[2][4];
#pragma unroll
  for (int i = 0; i < 2; ++i)
#pragma unroll
    for (int j = 0; j < 4; ++j) o[i][j] = (f32x4){0.f, 0.f, 0.f, 0.f};

  const int nch = qt / 2 + 1;
  bf16x8 kf[4][2], vf[4][2];
  if (w < nch) {
    const int s0 = w * 64;
#pragma unroll
    for (int st = 0; st < 4; ++st)
#pragma unroll
      for (int kh = 0; kh < 2; ++kh)
        kf[st][kh] = *reinterpret_cast<const bf16x8*>(
            &kb[(bT + s0 + st * 16 + l15) * NH + kh * 32 + lg * 8]);
#pragma unroll
    for (int ht = 0; ht < 4; ++ht)
#pragma unroll
      for (int sh = 0; sh < 2; ++sh)
        vf[ht][sh] = *reinterpret_cast<const bf16x8*>(
            &vt[((size_t)b * NH + ht * 16 + l15) * NT + s0 + sh * 32 + lg * 8]);
  }

  for (int c = w; c < nch; c += 4) {
    const int s0 = c * 64;
    f32x4 s[4][2];
#pragma unroll
    for (int st = 0; st < 4; ++st)
#pragma unroll
      for (int ct = 0; ct < 2; ++ct) s[st][ct] = (f32x4){0.f, 0.f, 0.f, 0.f};
    __builtin_amdgcn_s_setprio(1);
#pragma unroll
    for (int st = 0; st < 4; ++st)
#pragma unroll
      for (int ct = 0; ct < 2; ++ct)
#pragma unroll
        for (int kh = 0; kh < 2; ++kh)
          s[st][ct] = __builtin_amdgcn_mfma_f32_16x16x32_bf16(kf[st][kh], qf[ct][kh], s[st][ct], 0, 0, 0);
    __builtin_amdgcn_s_setprio(0);

    const int cn = c + 4;
    bf16x8 kfn[4][2], vfn[4][2];
    if (cn < nch) {
      const int sn = cn * 64;
#pragma unroll
      for (int st = 0; st < 4; ++st)
#pragma unroll
        for (int kh = 0; kh < 2; ++kh)
          kfn[st][kh] = *reinterpret_cast<const bf16x8*>(
              &kb[(bT + sn + st * 16 + l15) * NH + kh * 32 + lg * 8]);
#pragma unroll
      for (int ht = 0; ht < 4; ++ht)
#pragma unroll
        for (int sh = 0; sh < 2; ++sh)
          vfn[ht][sh] = *reinterpret_cast<const bf16x8*>(
              &vt[((size_t)b * NH + ht * 16 + l15) * NT + sn + sh * 32 + lg * 8]);
    }

    if (s0 + 63 > q0) {
#pragma unroll
      for (int st = 0; st < 4; ++st)
#pragma unroll
        for (int ct = 0; ct < 2; ++ct) {
          int qg = q0 + ct * 16 + l15;
#pragma unroll
          for (int r = 0; r < 4; ++r) {
            int sg = s0 + st * 16 + lg * 4 + r;
            if (sg > qg) s[st][ct][r] = -1e30f;
          }
        }
    }
    float scv[2];
#pragma unroll
    for (int ct = 0; ct < 2; ++ct) {
      float rmx = -1e30f;
#pragma unroll
      for (int st = 0; st < 4; ++st)
#pragma unroll
        for (int r = 0; r < 4; ++r) rmx = fmaxf(rmx, s[st][ct][r]);
      rmx = fmaxf(rmx, __shfl_xor(rmx, 16));
      rmx = fmaxf(rmx, __shfl_xor(rmx, 32));
      float mn = fmaxf(m[ct], rmx);
      float sc = __expf(m[ct] - mn);
      m[ct] = mn;
      float rs = 0.f;
#pragma unroll
      for (int st = 0; st < 4; ++st) {
        float p0 = __expf(s[st][ct][0] - mn);
        float p1 = __expf(s[st][ct][1] - mn);
        float p2 = __expf(s[st][ct][2] - mn);
        float p3 = __expf(s[st][ct][3] - mn);
        rs += (p0 + p1) + (p2 + p3);
        int sp = st * 16 + lg * 4;
        *reinterpret_cast<unsigned*>(&ps[w][ct * 16 + l15][sp]) = pack_bf2(p0, p1);
        *reinterpret_cast<unsigned*>(&ps[w][ct * 16 + l15][sp + 2]) = pack_bf2(p2, p3);
      }
      rs += __shfl_xor(rs, 16);
      rs += __shfl_xor(rs, 32);
      lsum[ct] = lsum[ct] * sc + rs;
      scv[ct] = sc;
    }
#pragma unroll
    for (int rt = 0; rt < 2; ++rt)
#pragma unroll
      for (int r = 0; r < 4; ++r) {
        float fsc = __shfl(scv[rt], lg * 4 + r, 64);
#pragma unroll
        for (int ht = 0; ht < 4; ++ht) o[rt][ht][r] *= fsc;
      }
    __builtin_amdgcn_s_setprio(1);
#pragma unroll
    for (int rt = 0; rt < 2; ++rt) {
      bf16x8 pf[2];
#pragma unroll
      for (int sh = 0; sh < 2; ++sh)
        pf[sh] = *reinterpret_cast<const bf16x8*>(&ps[w][rt * 16 + l15][sh * 32 + lg * 8]);
#pragma unroll
      for (int ht = 0; ht < 4; ++ht)
#pragma unroll
        for (int sh = 0; sh < 2; ++sh)
          o[rt][ht] = __builtin_amdgcn_mfma_f32_16x16x32_bf16(pf[sh], vf[ht][sh], o[rt][ht], 0, 0, 0);
    }
    __builtin_amdgcn_s_setprio(0);
    if (cn < nch) {
#pragma unroll
      for (int st = 0; st < 4; ++st)
#pragma unroll
        for (int kh = 0; kh < 2; ++kh) kf[st][kh] = kfn[st][kh];
#pragma unroll
      for (int ht = 0; ht < 4; ++ht)
#pragma unroll
        for (int sh = 0; sh < 2; ++sh) vf[ht][sh] = vfn[ht][sh];
    }
  }

  if (lg == 0) {
#pragma unroll
    for (int ct = 0; ct < 2; ++ct) {
      msh[w][ct * 16 + l15] = m[ct];
      lsh[w][ct * 16 + l15] = lsum[ct];
    }
  }
#pragma unroll
  for (int rt = 0; rt < 2; ++rt)
#pragma unroll
    for (int ht = 0; ht < 4; ++ht)
#pragma unroll
      for (int r = 0; r < 4; ++r)
        obuf[w][rt * 16 + lg * 4 + r][ht * 16 + l15] = o[rt][ht][r];
  __syncthreads();

  {
    int qr = tid >> 3, h8 = (tid & 7) * 8;
    float m0 = msh[0][qr], m1 = msh[1][qr], m2 = msh[2][qr], m3 = msh[3][qr];
    float M = fmaxf(fmaxf(m0, m1), fmaxf(m2, m3));
    float e0 = __expf(m0 - M), e1 = __expf(m1 - M);
    float e2 = __expf(m2 - M), e3 = __expf(m3 - M);
    float L = e0 * lsh[0][qr] + e1 * lsh[1][qr] + e2 * lsh[2][qr] + e3 * lsh[3][qr];
    float inv = 1.f / L;
#pragma unroll
    for (int i = 0; i < 8; ++i) {
      int h = h8 + i;
      float v = e0 * obuf[0][qr][h] + e1 * obuf[1][qr][h] +
                e2 * obuf[2][qr][h] + e3 * obuf[3][qr][h];
      out[(bT + q0 + qr) * NH + h] = v * inv;
    }
  }
}

extern "C" void kernel_launch(void* const* d_in, const int* in_sizes, int n_in,
                              void* d_out, int out_size, void* d_ws, size_t ws_size,
                              hipStream_t stream) {
  const float* x  = (const float*)d_in[0];
  const float* Wq = (const float*)d_in[1];
  const float* Wk = (const float*)d_in[2];
  const float* Wv = (const float*)d_in[3];
  float* out = (float*)d_out;

  char* ws = (char*)d_ws;
  __bf16* wt = (__bf16*)(ws);                        // 384 KB
  __bf16* qb = (__bf16*)(ws + 393216);               // 2 MB
  __bf16* kb = (__bf16*)(ws + 393216 + 2097152);     // 2 MB
  __bf16* vt = (__bf16*)(ws + 393216 + 2 * 2097152); // 2 MB

  wt_kernel<<<dim3(48), dim3(256), 0, stream>>>(Wq, Wk, Wv, wt);
  qkv_mfma_kernel<<<dim3(512), dim3(256), 0, stream>>>(x, wt, qb, kb, vt);
  attn_mfma_kernel<<<dim3(64, 8), dim3(256), 0, stream>>>(qb, kb, vt, out);
}

// Round 10
// 48.787 us; speedup vs baseline: 1.6298x; 1.6298x over previous
//
#include <hip/hip_runtime.h>

#define NB 8
#define NT 2048
#define NC 1024
#define NH 64

typedef __bf16 bf16x8 __attribute__((ext_vector_type(8)));
typedef float f32x4 __attribute__((ext_vector_type(4)));

static __device__ __forceinline__ float4 ldf4(const float* p) {
  return *reinterpret_cast<const float4*>(p);
}
static __device__ __forceinline__ bf16x8 ldb8(const __bf16* p) {
  return *reinterpret_cast<const bf16x8*>(p);
}
static __device__ __forceinline__ unsigned pack_bf2(float a, float b) {
  unsigned short ua = __builtin_bit_cast(unsigned short, (__bf16)a);
  unsigned short ub = __builtin_bit_cast(unsigned short, (__bf16)b);
  return (unsigned)ua | ((unsigned)ub << 16);
}

// ---------------------------------------------------------------------------
// Kernel A: Wt[192][1024] bf16 = transpose+convert of Wq|Wk|Wv (fp32 [1024][64]).
// ---------------------------------------------------------------------------
__global__ __launch_bounds__(256) void wt_kernel(
    const float* __restrict__ Wq, const float* __restrict__ Wk,
    const float* __restrict__ Wv, __bf16* __restrict__ wt) {
  __shared__ __bf16 tl[64][72];
  const int tid = threadIdx.x;
  const int mat = blockIdx.x >> 4;
  const int k0 = (blockIdx.x & 15) * 64;
  const float* W = (mat == 0) ? Wq : (mat == 1) ? Wk : Wv;
#pragma unroll
  for (int it = 0; it < 4; ++it) {
    int f = tid + it * 256;
    int kk = f >> 4, c4 = (f & 15) * 4;
    float4 w = ldf4(&W[(k0 + kk) * NH + c4]);
    tl[c4 + 0][kk] = (__bf16)w.x;
    tl[c4 + 1][kk] = (__bf16)w.y;
    tl[c4 + 2][kk] = (__bf16)w.z;
    tl[c4 + 3][kk] = (__bf16)w.w;
  }
  __syncthreads();
#pragma unroll
  for (int it = 0; it < 2; ++it) {
    int f = tid + it * 256;
    int h = f >> 3, k8 = (f & 7) * 8;
    *reinterpret_cast<bf16x8*>(&wt[(mat * 64 + h) * NC + k0 + k8]) =
        *reinterpret_cast<const bf16x8*>(&tl[h][k8]);
  }
}

// ---------------------------------------------------------------------------
// Kernel B: q,k (bf16 row-major) and v^T (bf16 [b][h][t]) = x @ W via MFMA.
// R4 skeleton (BM=32, BN=192, BK=64; 512 blocks x 256 thr = 4 waves,
// 2 blocks/CU; reg-staged LDS, 2 barriers/chunk) with DEPTH-2 PING-PONG
// register prefetch: two named load sets (sa*/sb*) alternate, so chunk t's
// loads are issued ~2 iterations before their LDS-write consumes them
// (issue-to-use gap ~2 iters instead of ~1 compute phase).
// Loads are unconditional (tail-clamped chunk index) to prevent sinking.
// ---------------------------------------------------------------------------
__global__ __launch_bounds__(256, 2) void qkv_mfma_kernel(
    const float* __restrict__ x, const __bf16* __restrict__ wt,
    __bf16* __restrict__ qb, __bf16* __restrict__ kb, __bf16* __restrict__ vt) {
  __shared__ __bf16 As[32][72];    // [row][k]
  __shared__ __bf16 Bs[192][72];   // [col][k]
  __shared__ __bf16 vls[64][40];   // [h][t_local] for v transpose
  const int tid = threadIdx.x;
  const int lane = tid & 63;
  const int w = tid >> 6;          // 0..3
  const int row0 = blockIdx.x * 32;
  const int csub = w * 48;
  const int l15 = lane & 15, lg = lane >> 4;

  f32x4 acc[2][3];
#pragma unroll
  for (int i = 0; i < 2; ++i)
#pragma unroll
    for (int j = 0; j < 3; ++j) acc[i][j] = (f32x4){0.f, 0.f, 0.f, 0.f};

  // staging thread->tile mapping (same as R4)
  const int ar0 = tid >> 4, ak0 = (tid & 15) * 4;            // A it=0
  const int ar1 = (tid + 256) >> 4, ak1 = ((tid + 256) & 15) * 4;  // A it=1
  int bcol[6], bk8[6];
#pragma unroll
  for (int it = 0; it < 6; ++it) {
    int f = tid + it * 256;
    bcol[it] = f >> 3;
    bk8[it] = (f & 7) * 8;
  }

  // ping-pong load sets (named, statically indexed)
  float4 saA0, saA1;  bf16x8 saB0, saB1, saB2, saB3, saB4, saB5;  // set A
  float4 sbA0, sbA1;  bf16x8 sbB0, sbB1, sbB2, sbB3, sbB4, sbB5;  // set B

  // prologue: set A <- chunk 0, set B <- chunk 1
  saA0 = ldf4(&x[(row0 + ar0) * NC + 0 + ak0]);
  saA1 = ldf4(&x[(row0 + ar1) * NC + 0 + ak1]);
  saB0 = ldb8(&wt[bcol[0] * NC + 0 + bk8[0]]);
  saB1 = ldb8(&wt[bcol[1] * NC + 0 + bk8[1]]);
  saB2 = ldb8(&wt[bcol[2] * NC + 0 + bk8[2]]);
  saB3 = ldb8(&wt[bcol[3] * NC + 0 + bk8[3]]);
  saB4 = ldb8(&wt[bcol[4] * NC + 0 + bk8[4]]);
  saB5 = ldb8(&wt[bcol[5] * NC + 0 + bk8[5]]);
  sbA0 = ldf4(&x[(row0 + ar0) * NC + 64 + ak0]);
  sbA1 = ldf4(&x[(row0 + ar1) * NC + 64 + ak1]);
  sbB0 = ldb8(&wt[bcol[0] * NC + 64 + bk8[0]]);
  sbB1 = ldb8(&wt[bcol[1] * NC + 64 + bk8[1]]);
  sbB2 = ldb8(&wt[bcol[2] * NC + 64 + bk8[2]]);
  sbB3 = ldb8(&wt[bcol[3] * NC + 64 + bk8[3]]);
  sbB4 = ldb8(&wt[bcol[4] * NC + 64 + bk8[4]]);
  sbB5 = ldb8(&wt[bcol[5] * NC + 64 + bk8[5]]);

#define QKV_COMPUTE()                                                          \
  _Pragma("unroll")                                                            \
  for (int kk = 0; kk < 2; ++kk) {                                             \
    bf16x8 af[2], bfr[3];                                                      \
    _Pragma("unroll")                                                          \
    for (int rt = 0; rt < 2; ++rt)                                             \
      af[rt] = ldb8(&As[rt * 16 + l15][kk * 32 + lg * 8]);                     \
    _Pragma("unroll")                                                          \
    for (int nt = 0; nt < 3; ++nt)                                             \
      bfr[nt] = ldb8(&Bs[csub + nt * 16 + l15][kk * 32 + lg * 8]);             \
    _Pragma("unroll")                                                          \
    for (int rt = 0; rt < 2; ++rt)                                             \
      _Pragma("unroll")                                                        \
      for (int nt = 0; nt < 3; ++nt)                                           \
        acc[rt][nt] =                                                          \
            __builtin_amdgcn_mfma_f32_16x16x32_bf16(af[rt], bfr[nt],           \
                                                    acc[rt][nt], 0, 0, 0);     \
  }

  for (int ch = 0; ch < 16; ch += 2) {
    // ---- even chunk ch: consume set A, reload set A with chunk ch+2 ----
    {
      uint2 u0 = {pack_bf2(saA0.x, saA0.y), pack_bf2(saA0.z, saA0.w)};
      uint2 u1 = {pack_bf2(saA1.x, saA1.y), pack_bf2(saA1.z, saA1.w)};
      *reinterpret_cast<uint2*>(&As[ar0][ak0]) = u0;
      *reinterpret_cast<uint2*>(&As[ar1][ak1]) = u1;
      *reinterpret_cast<bf16x8*>(&Bs[bcol[0]][bk8[0]]) = saB0;
      *reinterpret_cast<bf16x8*>(&Bs[bcol[1]][bk8[1]]) = saB1;
      *reinterpret_cast<bf16x8*>(&Bs[bcol[2]][bk8[2]]) = saB2;
      *reinterpret_cast<bf16x8*>(&Bs[bcol[3]][bk8[3]]) = saB3;
      *reinterpret_cast<bf16x8*>(&Bs[bcol[4]][bk8[4]]) = saB4;
      *reinterpret_cast<bf16x8*>(&Bs[bcol[5]][bk8[5]]) = saB5;
      __syncthreads();
      const int kn = ((ch + 2 < 16) ? ch + 2 : 15) * 64;  // clamped, unconditional
      saA0 = ldf4(&x[(row0 + ar0) * NC + kn + ak0]);
      saA1 = ldf4(&x[(row0 + ar1) * NC + kn + ak1]);
      saB0 = ldb8(&wt[bcol[0] * NC + kn + bk8[0]]);
      saB1 = ldb8(&wt[bcol[1] * NC + kn + bk8[1]]);
      saB2 = ldb8(&wt[bcol[2] * NC + kn + bk8[2]]);
      saB3 = ldb8(&wt[bcol[3] * NC + kn + bk8[3]]);
      saB4 = ldb8(&wt[bcol[4] * NC + kn + bk8[4]]);
      saB5 = ldb8(&wt[bcol[5] * NC + kn + bk8[5]]);
      QKV_COMPUTE();
      __syncthreads();
    }
    // ---- odd chunk ch+1: consume set B, reload set B with chunk ch+3 ----
    {
      uint2 u0 = {pack_bf2(sbA0.x, sbA0.y), pack_bf2(sbA0.z, sbA0.w)};
      uint2 u1 = {pack_bf2(sbA1.x, sbA1.y), pack_bf2(sbA1.z, sbA1.w)};
      *reinterpret_cast<uint2*>(&As[ar0][ak0]) = u0;
      *reinterpret_cast<uint2*>(&As[ar1][ak1]) = u1;
      *reinterpret_cast<bf16x8*>(&Bs[bcol[0]][bk8[0]]) = sbB0;
      *reinterpret_cast<bf16x8*>(&Bs[bcol[1]][bk8[1]]) = sbB1;
      *reinterpret_cast<bf16x8*>(&Bs[bcol[2]][bk8[2]]) = sbB2;
      *reinterpret_cast<bf16x8*>(&Bs[bcol[3]][bk8[3]]) = sbB3;
      *reinterpret_cast<bf16x8*>(&Bs[bcol[4]][bk8[4]]) = sbB4;
      *reinterpret_cast<bf16x8*>(&Bs[bcol[5]][bk8[5]]) = sbB5;
      __syncthreads();
      const int kn = ((ch + 3 < 16) ? ch + 3 : 15) * 64;  // clamped, unconditional
      sbA0 = ldf4(&x[(row0 + ar0) * NC + kn + ak0]);
      sbA1 = ldf4(&x[(row0 + ar1) * NC + kn + ak1]);
      sbB0 = ldb8(&wt[bcol[0] * NC + kn + bk8[0]]);
      sbB1 = ldb8(&wt[bcol[1] * NC + kn + bk8[1]]);
      sbB2 = ldb8(&wt[bcol[2] * NC + kn + bk8[2]]);
      sbB3 = ldb8(&wt[bcol[3] * NC + kn + bk8[3]]);
      sbB4 = ldb8(&wt[bcol[4] * NC + kn + bk8[4]]);
      sbB5 = ldb8(&wt[bcol[5] * NC + kn + bk8[5]]);
      QKV_COMPUTE();
      __syncthreads();
    }
  }
#undef QKV_COMPUTE

  // epilogue: D layout col=l15, row=lg*4+r. mat uniform per (w,nt).
#pragma unroll
  for (int rt = 0; rt < 2; ++rt) {
#pragma unroll
    for (int nt = 0; nt < 3; ++nt) {
      int colbase = csub + nt * 16;   // wave-uniform, multiple of 16
      int mat = colbase >> 6;
      int h = (colbase & 63) + l15;
      if (mat == 0) {
#pragma unroll
        for (int r = 0; r < 4; ++r) {
          int row = row0 + rt * 16 + lg * 4 + r;
          qb[row * NH + h] = (__bf16)(acc[rt][nt][r] * 0.125f);  // pre-scale q
        }
      } else if (mat == 1) {
#pragma unroll
        for (int r = 0; r < 4; ++r) {
          int row = row0 + rt * 16 + lg * 4 + r;
          kb[row * NH + h] = (__bf16)acc[rt][nt][r];
        }
      } else {
        ushort4 pk;
        pk.x = __builtin_bit_cast(unsigned short, (__bf16)acc[rt][nt][0]);
        pk.y = __builtin_bit_cast(unsigned short, (__bf16)acc[rt][nt][1]);
        pk.z = __builtin_bit_cast(unsigned short, (__bf16)acc[rt][nt][2]);
        pk.w = __builtin_bit_cast(unsigned short, (__bf16)acc[rt][nt][3]);
        *reinterpret_cast<ushort4*>(&vls[h][rt * 16 + lg * 4]) = pk;
      }
    }
  }
  __syncthreads();
  // cooperative coalesced v^T store: 64 h x 32 t, one 16B store per thread
  {
    int h = tid >> 2, t8 = (tid & 3) * 8;
    int bb = row0 >> 11;
    int t0l = row0 & (NT - 1);
    *reinterpret_cast<bf16x8*>(&vt[((size_t)bb * NH + h) * NT + t0l + t8]) =
        *reinterpret_cast<const bf16x8*>(&vls[h][t8]);
  }
}

// ---------------------------------------------------------------------------
// Kernel C: causal flash attention via MFMA, intra-block KV split.
// (exact R4 version) Grid dim3(64,8); qt = (y<4) ? 63-x : x. 4 waves;
// wave w handles KV chunks c = w, w+4, ... setprio(1) around MFMA clusters.
// ---------------------------------------------------------------------------
__global__ __launch_bounds__(256, 2) void attn_mfma_kernel(
    const __bf16* __restrict__ qb, const __bf16* __restrict__ kb,
    const __bf16* __restrict__ vt, float* __restrict__ out) {
  __shared__ __bf16 ps[4][32][72];
  __shared__ float obuf[4][32][68];
  __shared__ float msh[4][32], lsh[4][32];
  const int tid = threadIdx.x;
  const int lane = tid & 63;
  const int w = tid >> 6;
  const int l15 = lane & 15, lg = lane >> 4;
  const int b = blockIdx.y;
  const int qt = (blockIdx.y < 4) ? (63 - (int)blockIdx.x) : (int)blockIdx.x;
  const int q0 = qt * 32;
  const size_t bT = (size_t)b * NT;

  bf16x8 qf[2][2];
#pragma unroll
  for (int ct = 0; ct < 2; ++ct)
#pragma unroll
    for (int kh = 0; kh < 2; ++kh)
      qf[ct][kh] = *reinterpret_cast<const bf16x8*>(
          &qb[(bT + q0 + ct * 16 + l15) * NH + kh * 32 + lg * 8]);

  float m[2] = {-1e30f, -1e30f};
  float lsum[2] = {0.f, 0.f};
  f32x4 o[2][4];
#pragma unroll
  for (int i = 0; i < 2; ++i)
#pragma unroll
    for (int j = 0; j < 4; ++j) o[i][j] = (f32x4){0.f, 0.f, 0.f, 0.f};

  const int nch = qt / 2 + 1;
  bf16x8 kf[4][2], vf[4][2];
  if (w < nch) {
    const int s0 = w * 64;
#pragma unroll
    for (int st = 0; st < 4; ++st)
#pragma unroll
      for (int kh = 0; kh < 2; ++kh)
        kf[st][kh] = *reinterpret_cast<const bf16x8*>(
            &kb[(bT + s0 + st * 16 + l15) * NH + kh * 32 + lg * 8]);
#pragma unroll
    for (int ht = 0; ht < 4; ++ht)
#pragma unroll
      for (int sh = 0; sh < 2; ++sh)
        vf[ht][sh] = *reinterpret_cast<const bf16x8*>(
            &vt[((size_t)b * NH + ht * 16 + l15) * NT + s0 + sh * 32 + lg * 8]);
  }

  for (int c = w; c < nch; c += 4) {
    const int s0 = c * 64;
    f32x4 s[4][2];
#pragma unroll
    for (int st = 0; st < 4; ++st)
#pragma unroll
      for (int ct = 0; ct < 2; ++ct) s[st][ct] = (f32x4){0.f, 0.f, 0.f, 0.f};
    __builtin_amdgcn_s_setprio(1);
#pragma unroll
    for (int st = 0; st < 4; ++st)
#pragma unroll
      for (int ct = 0; ct < 2; ++ct)
#pragma unroll
        for (int kh = 0; kh < 2; ++kh)
          s[st][ct] = __builtin_amdgcn_mfma_f32_16x16x32_bf16(kf[st][kh], qf[ct][kh], s[st][ct], 0, 0, 0);
    __builtin_amdgcn_s_setprio(0);

    const int cn = c + 4;
    bf16x8 kfn[4][2], vfn[4][2];
    if (cn < nch) {
      const int sn = cn * 64;
#pragma unroll
      for (int st = 0; st < 4; ++st)
#pragma unroll
        for (int kh = 0; kh < 2; ++kh)
          kfn[st][kh] = *reinterpret_cast<const bf16x8*>(
              &kb[(bT + sn + st * 16 + l15) * NH + kh * 32 + lg * 8]);
#pragma unroll
      for (int ht = 0; ht < 4; ++ht)
#pragma unroll
        for (int sh = 0; sh < 2; ++sh)
          vfn[ht][sh] = *reinterpret_cast<const bf16x8*>(
              &vt[((size_t)b * NH + ht * 16 + l15) * NT + sn + sh * 32 + lg * 8]);
    }

    if (s0 + 63 > q0) {
#pragma unroll
      for (int st = 0; st < 4; ++st)
#pragma unroll
        for (int ct = 0; ct < 2; ++ct) {
          int qg = q0 + ct * 16 + l15;
#pragma unroll
          for (int r = 0; r < 4; ++r) {
            int sg = s0 + st * 16 + lg * 4 + r;
            if (sg > qg) s[st][ct][r] = -1e30f;
          }
        }
    }
    float scv[2];
#pragma unroll
    for (int ct = 0; ct < 2; ++ct) {
      float rmx = -1e30f;
#pragma unroll
      for (int st = 0; st < 4; ++st)
#pragma unroll
        for (int r = 0; r < 4; ++r) rmx = fmaxf(rmx, s[st][ct][r]);
      rmx = fmaxf(rmx, __shfl_xor(rmx, 16));
      rmx = fmaxf(rmx, __shfl_xor(rmx, 32));
      float mn = fmaxf(m[ct], rmx);
      float sc = __expf(m[ct] - mn);
      m[ct] = mn;
      float rs = 0.f;
#pragma unroll
      for (int st = 0; st < 4; ++st) {
        float p0 = __expf(s[st][ct][0] - mn);
        float p1 = __expf(s[st][ct][1] - mn);
        float p2 = __expf(s[st][ct][2] - mn);
        float p3 = __expf(s[st][ct][3] - mn);
        rs += (p0 + p1) + (p2 + p3);
        int sp = st * 16 + lg * 4;
        *reinterpret_cast<unsigned*>(&ps[w][ct * 16 + l15][sp]) = pack_bf2(p0, p1);
        *reinterpret_cast<unsigned*>(&ps[w][ct * 16 + l15][sp + 2]) = pack_bf2(p2, p3);
      }
      rs += __shfl_xor(rs, 16);
      rs += __shfl_xor(rs, 32);
      lsum[ct] = lsum[ct] * sc + rs;
      scv[ct] = sc;
    }
#pragma unroll
    for (int rt = 0; rt < 2; ++rt)
#pragma unroll
      for (int r = 0; r < 4; ++r) {
        float fsc = __shfl(scv[rt], lg * 4 + r, 64);
#pragma unroll
        for (int ht = 0; ht < 4; ++ht) o[rt][ht][r] *= fsc;
      }
    __builtin_amdgcn_s_setprio(1);
#pragma unroll
    for (int rt = 0; rt < 2; ++rt) {
      bf16x8 pf[2];
#pragma unroll
      for (int sh = 0; sh < 2; ++sh)
        pf[sh] = *reinterpret_cast<const bf16x8*>(&ps[w][rt * 16 + l15][sh * 32 + lg * 8]);
#pragma unroll
      for (int ht = 0; ht < 4; ++ht)
#pragma unroll
        for (int sh = 0; sh < 2; ++sh)
          o[rt][ht] = __builtin_amdgcn_mfma_f32_16x16x32_bf16(pf[sh], vf[ht][sh], o[rt][ht], 0, 0, 0);
    }
    __builtin_amdgcn_s_setprio(0);
    if (cn < nch) {
#pragma unroll
      for (int st = 0; st < 4; ++st)
#pragma unroll
        for (int kh = 0; kh < 2; ++kh) kf[st][kh] = kfn[st][kh];
#pragma unroll
      for (int ht = 0; ht < 4; ++ht)
#pragma unroll
        for (int sh = 0; sh < 2; ++sh) vf[ht][sh] = vfn[ht][sh];
    }
  }

  if (lg == 0) {
#pragma unroll
    for (int ct = 0; ct < 2; ++ct) {
      msh[w][ct * 16 + l15] = m[ct];
      lsh[w][ct * 16 + l15] = lsum[ct];
    }
  }
#pragma unroll
  for (int rt = 0; rt < 2; ++rt)
#pragma unroll
    for (int ht = 0; ht < 4; ++ht)
#pragma unroll
      for (int r = 0; r < 4; ++r)
        obuf[w][rt * 16 + lg * 4 + r][ht * 16 + l15] = o[rt][ht][r];
  __syncthreads();

  {
    int qr = tid >> 3, h8 = (tid & 7) * 8;
    float m0 = msh[0][qr], m1 = msh[1][qr], m2 = msh[2][qr], m3 = msh[3][qr];
    float M = fmaxf(fmaxf(m0, m1), fmaxf(m2, m3));
    float e0 = __expf(m0 - M), e1 = __expf(m1 - M);
    float e2 = __expf(m2 - M), e3 = __expf(m3 - M);
    float L = e0 * lsh[0][qr] + e1 * lsh[1][qr] + e2 * lsh[2][qr] + e3 * lsh[3][qr];
    float inv = 1.f / L;
#pragma unroll
    for (int i = 0; i < 8; ++i) {
      int h = h8 + i;
      float v = e0 * obuf[0][qr][h] + e1 * obuf[1][qr][h] +
                e2 * obuf[2][qr][h] + e3 * obuf[3][qr][h];
      out[(bT + q0 + qr) * NH + h] = v * inv;
    }
  }
}

extern "C" void kernel_launch(void* const* d_in, const int* in_sizes, int n_in,
                              void* d_out, int out_size, void* d_ws, size_t ws_size,
                              hipStream_t stream) {
  const float* x  = (const float*)d_in[0];
  const float* Wq = (const float*)d_in[1];
  const float* Wk = (const float*)d_in[2];
  const float* Wv = (const float*)d_in[3];
  float* out = (float*)d_out;

  char* ws = (char*)d_ws;
  __bf16* wt = (__bf16*)(ws);                        // 384 KB
  __bf16* qb = (__bf16*)(ws + 393216);               // 2 MB
  __bf16* kb = (__bf16*)(ws + 393216 + 2097152);     // 2 MB
  __bf16* vt = (__bf16*)(ws + 393216 + 2 * 2097152); // 2 MB

  wt_kernel<<<dim3(48), dim3(256), 0, stream>>>(Wq, Wk, Wv, wt);
  qkv_mfma_kernel<<<dim3(512), dim3(256), 0, stream>>>(x, wt, qb, kb, vt);
  attn_mfma_kernel<<<dim3(64, 8), dim3(256), 0, stream>>>(qb, kb, vt, out);
}

// Round 11
// 48.340 us; speedup vs baseline: 1.6449x; 1.0092x over previous
//
#include <hip/hip_runtime.h>

#define NB 8
#define NT 2048
#define NC 1024
#define NH 64

typedef __bf16 bf16x8 __attribute__((ext_vector_type(8)));
typedef float f32x4 __attribute__((ext_vector_type(4)));

static __device__ __forceinline__ float4 ldf4(const float* p) {
  return *reinterpret_cast<const float4*>(p);
}
static __device__ __forceinline__ bf16x8 ldb8(const __bf16* p) {
  return *reinterpret_cast<const bf16x8*>(p);
}
static __device__ __forceinline__ unsigned pack_bf2(float a, float b) {
  unsigned short ua = __builtin_bit_cast(unsigned short, (__bf16)a);
  unsigned short ub = __builtin_bit_cast(unsigned short, (__bf16)b);
  return (unsigned)ua | ((unsigned)ub << 16);
}

// ---------------------------------------------------------------------------
// Kernel A: Wt[192][1024] bf16 = transpose+convert of Wq|Wk|Wv (fp32 [1024][64]).
// ---------------------------------------------------------------------------
__global__ __launch_bounds__(256) void wt_kernel(
    const float* __restrict__ Wq, const float* __restrict__ Wk,
    const float* __restrict__ Wv, __bf16* __restrict__ wt) {
  __shared__ __bf16 tl[64][72];
  const int tid = threadIdx.x;
  const int mat = blockIdx.x >> 4;
  const int k0 = (blockIdx.x & 15) * 64;
  const float* W = (mat == 0) ? Wq : (mat == 1) ? Wk : Wv;
#pragma unroll
  for (int it = 0; it < 4; ++it) {
    int f = tid + it * 256;
    int kk = f >> 4, c4 = (f & 15) * 4;
    float4 w = ldf4(&W[(k0 + kk) * NH + c4]);
    tl[c4 + 0][kk] = (__bf16)w.x;
    tl[c4 + 1][kk] = (__bf16)w.y;
    tl[c4 + 2][kk] = (__bf16)w.z;
    tl[c4 + 3][kk] = (__bf16)w.w;
  }
  __syncthreads();
#pragma unroll
  for (int it = 0; it < 2; ++it) {
    int f = tid + it * 256;
    int h = f >> 3, k8 = (f & 7) * 8;
    *reinterpret_cast<bf16x8*>(&wt[(mat * 64 + h) * NC + k0 + k8]) =
        *reinterpret_cast<const bf16x8*>(&tl[h][k8]);
  }
}

// ---------------------------------------------------------------------------
// Kernel B: q,k (bf16 row-major) and v^T (bf16 [b][h][t]) = x @ W via MFMA.
// R10 skeleton (BM=32, BN=192, BK=64; 512 blocks x 256 thr, 2 blocks/CU;
// reg-staged, depth-2 ping-pong sets) with the vmcnt-drain REMOVED:
//  - LDS double-buffered (As[2]/Bs[2]) -> ONE barrier per chunk
//  - raw s_barrier + explicit lgkmcnt(0) (LDS visibility) -- NO vmcnt(0)
//    drain, so prefetch loads issued 2 phases ago stay in flight across
//    barriers; compiler emits counted vmcnt before each ds_write.
// Buffer reuse is 2 barriers apart -> no LDS read/write race.
// ---------------------------------------------------------------------------
__global__ __launch_bounds__(256, 2) void qkv_mfma_kernel(
    const float* __restrict__ x, const __bf16* __restrict__ wt,
    __bf16* __restrict__ qb, __bf16* __restrict__ kb, __bf16* __restrict__ vt) {
  __shared__ __bf16 As[2][32][72];   // [buf][row][k]
  __shared__ __bf16 Bs[2][192][72];  // [buf][col][k]
  __shared__ __bf16 vls[64][40];     // [h][t_local] for v transpose
  const int tid = threadIdx.x;
  const int lane = tid & 63;
  const int w = tid >> 6;          // 0..3
  const int row0 = blockIdx.x * 32;
  const int csub = w * 48;
  const int l15 = lane & 15, lg = lane >> 4;

  f32x4 acc[2][3];
#pragma unroll
  for (int i = 0; i < 2; ++i)
#pragma unroll
    for (int j = 0; j < 3; ++j) acc[i][j] = (f32x4){0.f, 0.f, 0.f, 0.f};

  // staging thread->tile mapping
  const int ar0 = tid >> 4, ak0 = (tid & 15) * 4;                  // A it=0
  const int ar1 = (tid + 256) >> 4, ak1 = ((tid + 256) & 15) * 4;  // A it=1
  int bcol[6], bk8[6];
#pragma unroll
  for (int it = 0; it < 6; ++it) {
    int f = tid + it * 256;
    bcol[it] = f >> 3;
    bk8[it] = (f & 7) * 8;
  }

  // ping-pong load sets (named, statically indexed)
  float4 saA0, saA1;  bf16x8 saB0, saB1, saB2, saB3, saB4, saB5;  // set A
  float4 sbA0, sbA1;  bf16x8 sbB0, sbB1, sbB2, sbB3, sbB4, sbB5;  // set B

  // prologue: set A <- chunk 0, set B <- chunk 1
  saA0 = ldf4(&x[(row0 + ar0) * NC + 0 + ak0]);
  saA1 = ldf4(&x[(row0 + ar1) * NC + 0 + ak1]);
  saB0 = ldb8(&wt[bcol[0] * NC + 0 + bk8[0]]);
  saB1 = ldb8(&wt[bcol[1] * NC + 0 + bk8[1]]);
  saB2 = ldb8(&wt[bcol[2] * NC + 0 + bk8[2]]);
  saB3 = ldb8(&wt[bcol[3] * NC + 0 + bk8[3]]);
  saB4 = ldb8(&wt[bcol[4] * NC + 0 + bk8[4]]);
  saB5 = ldb8(&wt[bcol[5] * NC + 0 + bk8[5]]);
  sbA0 = ldf4(&x[(row0 + ar0) * NC + 64 + ak0]);
  sbA1 = ldf4(&x[(row0 + ar1) * NC + 64 + ak1]);
  sbB0 = ldb8(&wt[bcol[0] * NC + 64 + bk8[0]]);
  sbB1 = ldb8(&wt[bcol[1] * NC + 64 + bk8[1]]);
  sbB2 = ldb8(&wt[bcol[2] * NC + 64 + bk8[2]]);
  sbB3 = ldb8(&wt[bcol[3] * NC + 64 + bk8[3]]);
  sbB4 = ldb8(&wt[bcol[4] * NC + 64 + bk8[4]]);
  sbB5 = ldb8(&wt[bcol[5] * NC + 64 + bk8[5]]);

#define QKV_COMPUTE(BUF)                                                       \
  _Pragma("unroll")                                                            \
  for (int kk = 0; kk < 2; ++kk) {                                             \
    bf16x8 af[2], bfr[3];                                                      \
    _Pragma("unroll")                                                          \
    for (int rt = 0; rt < 2; ++rt)                                             \
      af[rt] = ldb8(&As[BUF][rt * 16 + l15][kk * 32 + lg * 8]);                \
    _Pragma("unroll")                                                          \
    for (int nt = 0; nt < 3; ++nt)                                             \
      bfr[nt] = ldb8(&Bs[BUF][csub + nt * 16 + l15][kk * 32 + lg * 8]);        \
    _Pragma("unroll")                                                          \
    for (int rt = 0; rt < 2; ++rt)                                             \
      _Pragma("unroll")                                                        \
      for (int nt = 0; nt < 3; ++nt)                                           \
        acc[rt][nt] =                                                          \
            __builtin_amdgcn_mfma_f32_16x16x32_bf16(af[rt], bfr[nt],           \
                                                    acc[rt][nt], 0, 0, 0);     \
  }

  for (int ch = 0; ch < 16; ch += 2) {
    // ---- even chunk ch: buffer 0, set A; reload set A with chunk ch+2 ----
    {
      // ds_write (compiler inserts COUNTED vmcnt for set A's 8 loads only;
      // set B's 8 newer loads remain in flight)
      uint2 u0 = {pack_bf2(saA0.x, saA0.y), pack_bf2(saA0.z, saA0.w)};
      uint2 u1 = {pack_bf2(saA1.x, saA1.y), pack_bf2(saA1.z, saA1.w)};
      *reinterpret_cast<uint2*>(&As[0][ar0][ak0]) = u0;
      *reinterpret_cast<uint2*>(&As[0][ar1][ak1]) = u1;
      *reinterpret_cast<bf16x8*>(&Bs[0][bcol[0]][bk8[0]]) = saB0;
      *reinterpret_cast<bf16x8*>(&Bs[0][bcol[1]][bk8[1]]) = saB1;
      *reinterpret_cast<bf16x8*>(&Bs[0][bcol[2]][bk8[2]]) = saB2;
      *reinterpret_cast<bf16x8*>(&Bs[0][bcol[3]][bk8[3]]) = saB3;
      *reinterpret_cast<bf16x8*>(&Bs[0][bcol[4]][bk8[4]]) = saB4;
      *reinterpret_cast<bf16x8*>(&Bs[0][bcol[5]][bk8[5]]) = saB5;
      // issue set A loads for chunk ch+2 (clamped, unconditional)
      const int kn = ((ch + 2 < 16) ? ch + 2 : 15) * 64;
      saA0 = ldf4(&x[(row0 + ar0) * NC + kn + ak0]);
      saA1 = ldf4(&x[(row0 + ar1) * NC + kn + ak1]);
      saB0 = ldb8(&wt[bcol[0] * NC + kn + bk8[0]]);
      saB1 = ldb8(&wt[bcol[1] * NC + kn + bk8[1]]);
      saB2 = ldb8(&wt[bcol[2] * NC + kn + bk8[2]]);
      saB3 = ldb8(&wt[bcol[3] * NC + kn + bk8[3]]);
      saB4 = ldb8(&wt[bcol[4] * NC + kn + bk8[4]]);
      saB5 = ldb8(&wt[bcol[5] * NC + kn + bk8[5]]);
      // LDS visibility only -- NO vmcnt drain
      asm volatile("s_waitcnt lgkmcnt(0)" ::: "memory");
      __builtin_amdgcn_s_barrier();
      __builtin_amdgcn_sched_barrier(0);
      QKV_COMPUTE(0);
    }
    // ---- odd chunk ch+1: buffer 1, set B; reload set B with chunk ch+3 ----
    {
      uint2 u0 = {pack_bf2(sbA0.x, sbA0.y), pack_bf2(sbA0.z, sbA0.w)};
      uint2 u1 = {pack_bf2(sbA1.x, sbA1.y), pack_bf2(sbA1.z, sbA1.w)};
      *reinterpret_cast<uint2*>(&As[1][ar0][ak0]) = u0;
      *reinterpret_cast<uint2*>(&As[1][ar1][ak1]) = u1;
      *reinterpret_cast<bf16x8*>(&Bs[1][bcol[0]][bk8[0]]) = sbB0;
      *reinterpret_cast<bf16x8*>(&Bs[1][bcol[1]][bk8[1]]) = sbB1;
      *reinterpret_cast<bf16x8*>(&Bs[1][bcol[2]][bk8[2]]) = sbB2;
      *reinterpret_cast<bf16x8*>(&Bs[1][bcol[3]][bk8[3]]) = sbB3;
      *reinterpret_cast<bf16x8*>(&Bs[1][bcol[4]][bk8[4]]) = sbB4;
      *reinterpret_cast<bf16x8*>(&Bs[1][bcol[5]][bk8[5]]) = sbB5;
      const int kn = ((ch + 3 < 16) ? ch + 3 : 15) * 64;
      sbA0 = ldf4(&x[(row0 + ar0) * NC + kn + ak0]);
      sbA1 = ldf4(&x[(row0 + ar1) * NC + kn + ak1]);
      sbB0 = ldb8(&wt[bcol[0] * NC + kn + bk8[0]]);
      sbB1 = ldb8(&wt[bcol[1] * NC + kn + bk8[1]]);
      sbB2 = ldb8(&wt[bcol[2] * NC + kn + bk8[2]]);
      sbB3 = ldb8(&wt[bcol[3] * NC + kn + bk8[3]]);
      sbB4 = ldb8(&wt[bcol[4] * NC + kn + bk8[4]]);
      sbB5 = ldb8(&wt[bcol[5] * NC + kn + bk8[5]]);
      asm volatile("s_waitcnt lgkmcnt(0)" ::: "memory");
      __builtin_amdgcn_s_barrier();
      __builtin_amdgcn_sched_barrier(0);
      QKV_COMPUTE(1);
    }
  }
#undef QKV_COMPUTE

  // epilogue: D layout col=l15, row=lg*4+r. mat uniform per (w,nt).
  __syncthreads();  // full drain before LDS reuse for vls
#pragma unroll
  for (int rt = 0; rt < 2; ++rt) {
#pragma unroll
    for (int nt = 0; nt < 3; ++nt) {
      int colbase = csub + nt * 16;   // wave-uniform, multiple of 16
      int mat = colbase >> 6;
      int h = (colbase & 63) + l15;
      if (mat == 0) {
#pragma unroll
        for (int r = 0; r < 4; ++r) {
          int row = row0 + rt * 16 + lg * 4 + r;
          qb[row * NH + h] = (__bf16)(acc[rt][nt][r] * 0.125f);  // pre-scale q
        }
      } else if (mat == 1) {
#pragma unroll
        for (int r = 0; r < 4; ++r) {
          int row = row0 + rt * 16 + lg * 4 + r;
          kb[row * NH + h] = (__bf16)acc[rt][nt][r];
        }
      } else {
        ushort4 pk;
        pk.x = __builtin_bit_cast(unsigned short, (__bf16)acc[rt][nt][0]);
        pk.y = __builtin_bit_cast(unsigned short, (__bf16)acc[rt][nt][1]);
        pk.z = __builtin_bit_cast(unsigned short, (__bf16)acc[rt][nt][2]);
        pk.w = __builtin_bit_cast(unsigned short, (__bf16)acc[rt][nt][3]);
        *reinterpret_cast<ushort4*>(&vls[h][rt * 16 + lg * 4]) = pk;
      }
    }
  }
  __syncthreads();
  // cooperative coalesced v^T store: 64 h x 32 t, one 16B store per thread
  {
    int h = tid >> 2, t8 = (tid & 3) * 8;
    int bb = row0 >> 11;
    int t0l = row0 & (NT - 1);
    *reinterpret_cast<bf16x8*>(&vt[((size_t)bb * NH + h) * NT + t0l + t8]) =
        *reinterpret_cast<const bf16x8*>(&vls[h][t8]);
  }
}

// ---------------------------------------------------------------------------
// Kernel C: causal flash attention via MFMA, intra-block KV split.
// (exact R4 version) Grid dim3(64,8); qt = (y<4) ? 63-x : x. 4 waves;
// wave w handles KV chunks c = w, w+4, ... setprio(1) around MFMA clusters.
// ---------------------------------------------------------------------------
__global__ __launch_bounds__(256, 2) void attn_mfma_kernel(
    const __bf16* __restrict__ qb, const __bf16* __restrict__ kb,
    const __bf16* __restrict__ vt, float* __restrict__ out) {
  __shared__ __bf16 ps[4][32][72];
  __shared__ float obuf[4][32][68];
  __shared__ float msh[4][32], lsh[4][32];
  const int tid = threadIdx.x;
  const int lane = tid & 63;
  const int w = tid >> 6;
  const int l15 = lane & 15, lg = lane >> 4;
  const int b = blockIdx.y;
  const int qt = (blockIdx.y < 4) ? (63 - (int)blockIdx.x) : (int)blockIdx.x;
  const int q0 = qt * 32;
  const size_t bT = (size_t)b * NT;

  bf16x8 qf[2][2];
#pragma unroll
  for (int ct = 0; ct < 2; ++ct)
#pragma unroll
    for (int kh = 0; kh < 2; ++kh)
      qf[ct][kh] = *reinterpret_cast<const bf16x8*>(
          &qb[(bT + q0 + ct * 16 + l15) * NH + kh * 32 + lg * 8]);

  float m[2] = {-1e30f, -1e30f};
  float lsum[2] = {0.f, 0.f};
  f32x4 o[2][4];
#pragma unroll
  for (int i = 0; i < 2; ++i)
#pragma unroll
    for (int j = 0; j < 4; ++j) o[i][j] = (f32x4){0.f, 0.f, 0.f, 0.f};

  const int nch = qt / 2 + 1;
  bf16x8 kf[4][2], vf[4][2];
  if (w < nch) {
    const int s0 = w * 64;
#pragma unroll
    for (int st = 0; st < 4; ++st)
#pragma unroll
      for (int kh = 0; kh < 2; ++kh)
        kf[st][kh] = *reinterpret_cast<const bf16x8*>(
            &kb[(bT + s0 + st * 16 + l15) * NH + kh * 32 + lg * 8]);
#pragma unroll
    for (int ht = 0; ht < 4; ++ht)
#pragma unroll
      for (int sh = 0; sh < 2; ++sh)
        vf[ht][sh] = *reinterpret_cast<const bf16x8*>(
            &vt[((size_t)b * NH + ht * 16 + l15) * NT + s0 + sh * 32 + lg * 8]);
  }

  for (int c = w; c < nch; c += 4) {
    const int s0 = c * 64;
    f32x4 s[4][2];
#pragma unroll
    for (int st = 0; st < 4; ++st)
#pragma unroll
      for (int ct = 0; ct < 2; ++ct) s[st][ct] = (f32x4){0.f, 0.f, 0.f, 0.f};
    __builtin_amdgcn_s_setprio(1);
#pragma unroll
    for (int st = 0; st < 4; ++st)
#pragma unroll
      for (int ct = 0; ct < 2; ++ct)
#pragma unroll
        for (int kh = 0; kh < 2; ++kh)
          s[st][ct] = __builtin_amdgcn_mfma_f32_16x16x32_bf16(kf[st][kh], qf[ct][kh], s[st][ct], 0, 0, 0);
    __builtin_amdgcn_s_setprio(0);

    const int cn = c + 4;
    bf16x8 kfn[4][2], vfn[4][2];
    if (cn < nch) {
      const int sn = cn * 64;
#pragma unroll
      for (int st = 0; st < 4; ++st)
#pragma unroll
        for (int kh = 0; kh < 2; ++kh)
          kfn[st][kh] = *reinterpret_cast<const bf16x8*>(
              &kb[(bT + sn + st * 16 + l15) * NH + kh * 32 + lg * 8]);
#pragma unroll
      for (int ht = 0; ht < 4; ++ht)
#pragma unroll
        for (int sh = 0; sh < 2; ++sh)
          vfn[ht][sh] = *reinterpret_cast<const bf16x8*>(
              &vt[((size_t)b * NH + ht * 16 + l15) * NT + sn + sh * 32 + lg * 8]);
    }

    if (s0 + 63 > q0) {
#pragma unroll
      for (int st = 0; st < 4; ++st)
#pragma unroll
        for (int ct = 0; ct < 2; ++ct) {
          int qg = q0 + ct * 16 + l15;
#pragma unroll
          for (int r = 0; r < 4; ++r) {
            int sg = s0 + st * 16 + lg * 4 + r;
            if (sg > qg) s[st][ct][r] = -1e30f;
          }
        }
    }
    float scv[2];
#pragma unroll
    for (int ct = 0; ct < 2; ++ct) {
      float rmx = -1e30f;
#pragma unroll
      for (int st = 0; st < 4; ++st)
#pragma unroll
        for (int r = 0; r < 4; ++r) rmx = fmaxf(rmx, s[st][ct][r]);
      rmx = fmaxf(rmx, __shfl_xor(rmx, 16));
      rmx = fmaxf(rmx, __shfl_xor(rmx, 32));
      float mn = fmaxf(m[ct], rmx);
      float sc = __expf(m[ct] - mn);
      m[ct] = mn;
      float rs = 0.f;
#pragma unroll
      for (int st = 0; st < 4; ++st) {
        float p0 = __expf(s[st][ct][0] - mn);
        float p1 = __expf(s[st][ct][1] - mn);
        float p2 = __expf(s[st][ct][2] - mn);
        float p3 = __expf(s[st][ct][3] - mn);
        rs += (p0 + p1) + (p2 + p3);
        int sp = st * 16 + lg * 4;
        *reinterpret_cast<unsigned*>(&ps[w][ct * 16 + l15][sp]) = pack_bf2(p0, p1);
        *reinterpret_cast<unsigned*>(&ps[w][ct * 16 + l15][sp + 2]) = pack_bf2(p2, p3);
      }
      rs += __shfl_xor(rs, 16);
      rs += __shfl_xor(rs, 32);
      lsum[ct] = lsum[ct] * sc + rs;
      scv[ct] = sc;
    }
#pragma unroll
    for (int rt = 0; rt < 2; ++rt)
#pragma unroll
      for (int r = 0; r < 4; ++r) {
        float fsc = __shfl(scv[rt], lg * 4 + r, 64);
#pragma unroll
        for (int ht = 0; ht < 4; ++ht) o[rt][ht][r] *= fsc;
      }
    __builtin_amdgcn_s_setprio(1);
#pragma unroll
    for (int rt = 0; rt < 2; ++rt) {
      bf16x8 pf[2];
#pragma unroll
      for (int sh = 0; sh < 2; ++sh)
        pf[sh] = *reinterpret_cast<const bf16x8*>(&ps[w][rt * 16 + l15][sh * 32 + lg * 8]);
#pragma unroll
      for (int ht = 0; ht < 4; ++ht)
#pragma unroll
        for (int sh = 0; sh < 2; ++sh)
          o[rt][ht] = __builtin_amdgcn_mfma_f32_16x16x32_bf16(pf[sh], vf[ht][sh], o[rt][ht], 0, 0, 0);
    }
    __builtin_amdgcn_s_setprio(0);
    if (cn < nch) {
#pragma unroll
      for (int st = 0; st < 4; ++st)
#pragma unroll
        for (int kh = 0; kh < 2; ++kh) kf[st][kh] = kfn[st][kh];
#pragma unroll
      for (int ht = 0; ht < 4; ++ht)
#pragma unroll
        for (int sh = 0; sh < 2; ++sh) vf[ht][sh] = vfn[ht][sh];
    }
  }

  if (lg == 0) {
#pragma unroll
    for (int ct = 0; ct < 2; ++ct) {
      msh[w][ct * 16 + l15] = m[ct];
      lsh[w][ct * 16 + l15] = lsum[ct];
    }
  }
#pragma unroll
  for (int rt = 0; rt < 2; ++rt)
#pragma unroll
    for (int ht = 0; ht < 4; ++ht)
#pragma unroll
      for (int r = 0; r < 4; ++r)
        obuf[w][rt * 16 + lg * 4 + r][ht * 16 + l15] = o[rt][ht][r];
  __syncthreads();

  {
    int qr = tid >> 3, h8 = (tid & 7) * 8;
    float m0 = msh[0][qr], m1 = msh[1][qr], m2 = msh[2][qr], m3 = msh[3][qr];
    float M = fmaxf(fmaxf(m0, m1), fmaxf(m2, m3));
    float e0 = __expf(m0 - M), e1 = __expf(m1 - M);
    float e2 = __expf(m2 - M), e3 = __expf(m3 - M);
    float L = e0 * lsh[0][qr] + e1 * lsh[1][qr] + e2 * lsh[2][qr] + e3 * lsh[3][qr];
    float inv = 1.f / L;
#pragma unroll
    for (int i = 0; i < 8; ++i) {
      int h = h8 + i;
      float v = e0 * obuf[0][qr][h] + e1 * obuf[1][qr][h] +
                e2 * obuf[2][qr][h] + e3 * obuf[3][qr][h];
      out[(bT + q0 + qr) * NH + h] = v * inv;
    }
  }
}

extern "C" void kernel_launch(void* const* d_in, const int* in_sizes, int n_in,
                              void* d_out, int out_size, void* d_ws, size_t ws_size,
                              hipStream_t stream) {
  const float* x  = (const float*)d_in[0];
  const float* Wq = (const float*)d_in[1];
  const float* Wk = (const float*)d_in[2];
  const float* Wv = (const float*)d_in[3];
  float* out = (float*)d_out;

  char* ws = (char*)d_ws;
  __bf16* wt = (__bf16*)(ws);                        // 384 KB
  __bf16* qb = (__bf16*)(ws + 393216);               // 2 MB
  __bf16* kb = (__bf16*)(ws + 393216 + 2097152);     // 2 MB
  __bf16* vt = (__bf16*)(ws + 393216 + 2 * 2097152); // 2 MB

  wt_kernel<<<dim3(48), dim3(256), 0, stream>>>(Wq, Wk, Wv, wt);
  qkv_mfma_kernel<<<dim3(512), dim3(256), 0, stream>>>(x, wt, qb, kb, vt);
  attn_mfma_kernel<<<dim3(64, 8), dim3(256), 0, stream>>>(qb, kb, vt, out);
}